// Round 4
// baseline (237.575 us; speedup 1.0000x reference)
//
#include <hip/hip_runtime.h>

// YOLO layer: (64, 3*85, 44, 44) -> (64, 3*44*44, 85), fp32. Memory-bound:
// 253 MB traffic -> ~40 us roofline. R1-R3 stuck at ~80 us / 2.5 TB/s with
// VALUBusy*dur == 25 us const: block-wide barrier convoy serializes
// read/write phases. R4: barrier-free per-wave tiles (16 spatial x 85 ch,
// stride-85 odd = conflict-free), 2-deep cross-tile register pipeline,
// phase 2 = pure ds_read_b128 -> dwordx4 contiguous copy (no div).

#define NA       3
#define NC       80
#define GRIDW    44
#define SPATIAL  (GRIDW * GRIDW)     // 1936
#define CH       (5 + NC)            // 85
#define TS       16                  // spatial per wave-tile; 1936 = 121*16 exact
#define TPB      (SPATIAL / TS)      // 121 tiles per (b,a)
#define NT       4                   // tiles per wave
#define NW       4                   // waves per block (256 thr)
#define TOTT     (64 * NA * TPB)     // 23232 tiles
#define NBLK     (TOTT / (NT * NW))  // 1452 blocks -> all resident (6/CU via LDS)
#define STRIDE_F 8.0f                // 352/44; cancels /STRIDE in scaled anchors

__device__ __forceinline__ float sigf(float x) {
    return 1.0f / (1.0f + __expf(-x));
}

__global__ __launch_bounds__(256, 6)
void yolo_kernel(const float* __restrict__ in, float* __restrict__ out) {
    __shared__ float lds[NW][TS * CH];   // 4 x 5440 B = 21,760 B -> 6 blocks/CU

    const int tid  = threadIdx.x;
    const int w    = tid >> 6;
    const int lane = tid & 63;
    const int cg   = lane >> 2;          // channel-within-group 0..15
    const int sq   = (lane & 3) * 4;     // spatial quad start {0,4,8,12}

    const int t0 = (blockIdx.x * NW + w) * NT;   // first tile of this wave
    float* const myld = lds[w];

    float4 buf[2][6];

    // issue all 6 float4 loads of tile T (85 ch x 16 sp = 5.44 KB / wave)
    auto load_tile = [&](int T, float4* d) {
        int ba = T / TPB;
        int tl = T - ba * TPB;
        const float* ib = in + (size_t)ba * CH * SPATIAL + tl * TS;
        #pragma unroll
        for (int j = 0; j < 6; ++j) {
            int c = j * 16 + cg;                  // j=5: only cg<5 valid (c<85)
            if (j < 5 || cg < 5)
                d[j] = *(const float4*)(ib + (size_t)c * SPATIAL + sq);
        }
    };

    load_tile(t0, buf[0]);

    #pragma unroll
    for (int it = 0; it < NT; ++it) {
        const int T = t0 + it;
        if (it + 1 < NT) load_tile(T + 1, buf[(it + 1) & 1]);  // prefetch next

        float4* cur = buf[it & 1];
        const int ba = T / TPB;
        const int tl = T - ba * TPB;
        const int s0 = tl * TS;
        const int a  = ba % NA;
        const float aw = (a == 0) ? 10.0f : (a == 1) ? 16.0f : 33.0f;
        const float ah = (a == 0) ? 13.0f : (a == 1) ? 30.0f : 23.0f;

        // ---- transform + transpose into this wave's LDS tile ----
        #pragma unroll
        for (int j = 0; j < 6; ++j) {
            if (j == 5 && cg >= 5) continue;
            int c = j * 16 + cg;
            float r[4] = {cur[j].x, cur[j].y, cur[j].z, cur[j].w};
            #pragma unroll
            for (int e = 0; e < 4; ++e) {
                int   s = sq + e;
                float x = r[e];
                float o;
                if (c == 0)      { int gs = s0 + s; o = (sigf(x) + (float)(gs % GRIDW)) * STRIDE_F; }
                else if (c == 1) { int gs = s0 + s; o = (sigf(x) + (float)(gs / GRIDW)) * STRIDE_F; }
                else if (c == 2) o = __expf(x) * aw;
                else if (c == 3) o = __expf(x) * ah;
                else             o = sigf(x);     // conf + 80 classes
                myld[s * CH + c] = o;             // stride 85 (odd): 2/bank, free
            }
        }
        // same-wave ds_write -> ds_read: compiler inserts lgkmcnt wait; no barrier

        // ---- stream out: 1360 floats contiguous = 340 float4 (1 KB/wave-instr) ----
        float* ob = out + (size_t)T * (TS * CH);
        #pragma unroll
        for (int i = 0; i < 6; ++i) {
            int k4 = lane + i * 64;
            if (k4 < 340)
                *(float4*)(ob + k4 * 4) = *(const float4*)(myld + k4 * 4);
        }
    }
}

extern "C" void kernel_launch(void* const* d_in, const int* in_sizes, int n_in,
                              void* d_out, int out_size, void* d_ws, size_t ws_size,
                              hipStream_t stream) {
    const float* in = (const float*)d_in[0];
    float* out = (float*)d_out;
    yolo_kernel<<<NBLK, 256, 0, stream>>>(in, out);   // 1452 blocks, one shot
}